// Round 1
// baseline (32367.276 us; speedup 1.0000x reference)
//
#include <hip/hip_runtime.h>
#include <math.h>

// Problem constants
constexpr int B_  = 2;
constexpr int T_  = 2048;
constexpr int H_  = 12;
constexpr int C_  = 768;
constexpr int D_  = 64;
constexpr int FF_ = 3072;
constexpr int L_  = 12;
constexpr int VP_ = 4098;
constexpr int VF_ = 4096;
constexpr int BT_ = B_ * T_;   // 4096

// ---------------------------------------------------------------------------
// Embedding gather: x[row] = (ttype==1 ? feat_emb[tok] : pos_emb[tok])
// ---------------------------------------------------------------------------
__global__ __launch_bounds__(256) void embed_kernel(
    const int* __restrict__ tokens, const int* __restrict__ ttype,
    const float* __restrict__ pos_w, const float* __restrict__ feat_w,
    float* __restrict__ x) {
  int row = blockIdx.x;
  int tok = tokens[row];
  const float* src;
  if (ttype[row] == 1) {
    int t = min(max(tok, 0), VF_ - 1);
    src = feat_w + (size_t)t * C_;
  } else {
    int t = min(max(tok, 0), VP_ - 1);
    src = pos_w + (size_t)t * C_;
  }
  float* dst = x + (size_t)row * C_;
  for (int c = threadIdx.x; c < C_; c += 256) dst[c] = src[c];
}

// ---------------------------------------------------------------------------
// LayerNorm over C=768; one block (256 threads) per row.
// ---------------------------------------------------------------------------
__global__ __launch_bounds__(256) void ln_kernel(
    const float* __restrict__ x, const float* __restrict__ w,
    const float* __restrict__ b, float* __restrict__ out) {
  int row = blockIdx.x;
  const float* xr = x + (size_t)row * C_;
  float vv[3];
  float s = 0.f, s2 = 0.f;
#pragma unroll
  for (int i = 0; i < 3; i++) {
    float t = xr[threadIdx.x + i * 256];
    vv[i] = t; s += t; s2 += t * t;
  }
#pragma unroll
  for (int off = 32; off; off >>= 1) {
    s  += __shfl_xor(s,  off, 64);
    s2 += __shfl_xor(s2, off, 64);
  }
  __shared__ float ss[4], ss2[4];
  int wave = threadIdx.x >> 6, lane = threadIdx.x & 63;
  if (lane == 0) { ss[wave] = s; ss2[wave] = s2; }
  __syncthreads();
  s  = ss[0] + ss[1] + ss[2] + ss[3];
  s2 = ss2[0] + ss2[1] + ss2[2] + ss2[3];
  float mean = s * (1.f / C_);
  float var  = s2 * (1.f / C_) - mean * mean;
  float inv  = 1.f / sqrtf(var + 1e-5f);
  float* orow = out + (size_t)row * C_;
#pragma unroll
  for (int i = 0; i < 3; i++) {
    int c = threadIdx.x + i * 256;
    orow[c] = (vv[i] - mean) * inv * w[c] + b[c];
  }
}

// ---------------------------------------------------------------------------
// Generic GEMM: Co[M,N] = epilogue(A[M,K] @ W[N,K]^T)
// EPI: 0 = plain, 1 = exact GELU, 2 = Co = (*skip_p)*resid + (*rs_p)*acc
// 64x64 tile, BK=16, 256 threads, 4x4 micro-tile per thread.
// M must be a multiple of 64 and K a multiple of 16 (true for all uses).
// N may be ragged (VP=4098).
// ---------------------------------------------------------------------------
template <int EPI>
__global__ __launch_bounds__(256) void gemm_xwT(
    const float* __restrict__ A, const float* __restrict__ W,
    float* Co, const float* resid,
    const float* __restrict__ skip_p, const float* __restrict__ rs_p,
    int M, int N, int K) {
  constexpr int BK = 16;
  __shared__ float As[BK][68];   // [k][m], pad to 68 for aligned float4 reads
  __shared__ float Ws[BK][68];   // [k][n]
  int bm = blockIdx.y * 64, bn = blockIdx.x * 64;
  int tid = threadIdx.x;
  int tn = tid & 15, tm = tid >> 4;      // 16 x 16 thread grid
  int lr = tid >> 2;                      // staging row 0..63
  int lk = (tid & 3) * 4;                 // staging k offset 0,4,8,12

  float acc[4][4] = {};

  for (int k0 = 0; k0 < K; k0 += BK) {
    const float* ap = A + (size_t)(bm + lr) * K + k0 + lk;
    float4 av = *(const float4*)ap;
    float4 wv = make_float4(0.f, 0.f, 0.f, 0.f);
    int wrow = bn + lr;
    if (wrow < N) wv = *(const float4*)(W + (size_t)wrow * K + k0 + lk);
    As[lk + 0][lr] = av.x; As[lk + 1][lr] = av.y;
    As[lk + 2][lr] = av.z; As[lk + 3][lr] = av.w;
    Ws[lk + 0][lr] = wv.x; Ws[lk + 1][lr] = wv.y;
    Ws[lk + 2][lr] = wv.z; Ws[lk + 3][lr] = wv.w;
    __syncthreads();
#pragma unroll
    for (int kk = 0; kk < BK; kk++) {
      float4 a4 = *(const float4*)&As[kk][tm * 4];
      float4 b4 = *(const float4*)&Ws[kk][tn * 4];
      float a[4] = {a4.x, a4.y, a4.z, a4.w};
      float b[4] = {b4.x, b4.y, b4.z, b4.w};
#pragma unroll
      for (int i = 0; i < 4; i++)
#pragma unroll
        for (int j = 0; j < 4; j++) acc[i][j] += a[i] * b[j];
    }
    __syncthreads();
  }

  float skip = 0.f, rs = 0.f;
  if constexpr (EPI == 2) { skip = *skip_p; rs = *rs_p; }
#pragma unroll
  for (int i = 0; i < 4; i++) {
    int m = bm + tm * 4 + i;
#pragma unroll
    for (int j = 0; j < 4; j++) {
      int n = bn + tn * 4 + j;
      if (n < N) {
        size_t idx = (size_t)m * N + n;
        float c = acc[i][j];
        if constexpr (EPI == 1) c = 0.5f * c * (1.f + erff(c * 0.70710678118654752f));
        if constexpr (EPI == 2) c = skip * resid[idx] + rs * c;
        Co[idx] = c;
      }
    }
  }
}

// ---------------------------------------------------------------------------
// QKNorm + RoPE3D, in-place on qkv (BT, 3C). Block per row; wave per
// (head, q/k) group of 64 dims. v untouched.
// ---------------------------------------------------------------------------
__global__ __launch_bounds__(256) void qknorm_rope_kernel(
    float* __restrict__ qkv, const int* __restrict__ coords,
    const float* __restrict__ qscale, const float* __restrict__ kscale) {
  int row = blockIdx.x;
  int wave = threadIdx.x >> 6, lane = threadIdx.x & 63;
  int c0 = coords[row * 3 + 0];
  int c1 = coords[row * 3 + 1];
  int c2 = coords[row * 3 + 2];
  for (int g = wave; g < 2 * H_; g += 4) {
    int h = g >> 1, isk = g & 1;
    size_t idx = (size_t)row * (3 * C_) + (size_t)isk * C_ + h * D_ + lane;
    float v = qkv[idx];
    float ssum = v * v;
#pragma unroll
    for (int off = 32; off; off >>= 1) ssum += __shfl_xor(ssum, off, 64);
    float n = sqrtf(ssum * (1.f / D_) + 1e-6f);
    const float* sc = isk ? kscale : qscale;
    float xn = v / n * sc[lane];
    float partner = __shfl_xor(xn, 1, 64);
    float outv = xn;
    if (lane < 60) {
      int p = lane >> 1;
      int axis = p / 10;
      int f = p - axis * 10;
      int crd = (axis == 0) ? c0 : ((axis == 1) ? c1 : c2);
      // inv_freq = 10000^(-f/10) = exp(-f/10 * ln(10000))
      float invf = expf(-(float)f * 0.1f * 9.210340371976184f);
      float ang = (float)crd * invf;
      float sn, cs;
      sincosf(ang, &sn, &cs);
      if (lane & 1) {
        // odd lane: x1 = partner(even dim), x2 = self
        outv = partner * sn + xn * cs;
      } else {
        // even lane: x1 = self, x2 = partner(odd dim)
        outv = xn * cs - partner * sn;
      }
    }
    qkv[idx] = outv;
  }
}

// ---------------------------------------------------------------------------
// Causal flash attention. Block = 4 consecutive queries of one (b,h);
// wave w owns query q0+w; lane owns output dim. K/V tiles of 64 in LDS.
// qkv layout: (BT, 3C); q at col h*D+d, k at C + h*D+d, v at 2C + h*D+d.
// out: (BT, C) at col h*D+d.
// ---------------------------------------------------------------------------
__global__ __launch_bounds__(256) void attn_kernel(
    const float* __restrict__ qkv, float* __restrict__ out) {
  int bh = blockIdx.y;
  int b = bh / H_, h = bh % H_;
  int q0 = blockIdx.x * 4;
  int wave = threadIdx.x >> 6, lane = threadIdx.x & 63;
  int q = q0 + wave;

  __shared__ float Ks[64][65];
  __shared__ float Vs[64][65];
  __shared__ float Qs[4][64];
  Qs[wave][lane] = qkv[(size_t)(b * T_ + q) * (3 * C_) + h * D_ + lane];

  float m = -1e30f, lsum = 0.f, oacc = 0.f;
  int nk = q0 + 4;  // number of keys any wave in this block can see

  for (int k0 = 0; k0 < nk; k0 += 64) {
    int kt = min(64, nk - k0);
    __syncthreads();  // protect prior-iter reads of Ks/Vs; publishes Qs on iter 0
    for (int i = threadIdx.x; i < 64 * 64; i += 256) {
      int r = i >> 6, cdim = i & 63;
      if (r < kt) {
        size_t base = (size_t)(b * T_ + k0 + r) * (3 * C_) + h * D_ + cdim;
        Ks[r][cdim] = qkv[base + C_];
        Vs[r][cdim] = qkv[base + 2 * C_];
      }
    }
    __syncthreads();

    // score for key j = k0 + lane
    float s = 0.f;
#pragma unroll
    for (int d = 0; d < 64; d++) s += Qs[wave][d] * Ks[lane][d];
    bool valid = (lane < kt) && (k0 + lane <= q);
    s = valid ? s * 0.125f : -1e30f;

    float tmax = s;
#pragma unroll
    for (int off = 32; off; off >>= 1) tmax = fmaxf(tmax, __shfl_xor(tmax, off, 64));
    float mnew = fmaxf(m, tmax);
    float p = valid ? expf(s - mnew) : 0.f;
    float psum = p;
#pragma unroll
    for (int off = 32; off; off >>= 1) psum += __shfl_xor(psum, off, 64);
    float alpha = expf(m - mnew);
    lsum = lsum * alpha + psum;
    oacc *= alpha;
    m = mnew;

    for (int jj = 0; jj < kt; jj++) {
      float pj = __shfl(p, jj, 64);
      oacc += pj * Vs[jj][lane];
    }
  }

  out[(size_t)(b * T_ + q) * C_ + h * D_ + lane] = oacc / lsum;
}

// ---------------------------------------------------------------------------
// Orchestration
// ---------------------------------------------------------------------------
extern "C" void kernel_launch(void* const* d_in, const int* in_sizes, int n_in,
                              void* d_out, int out_size, void* d_ws, size_t ws_size,
                              hipStream_t stream) {
  const int*   tokens    = (const int*)d_in[0];
  const int*   coords    = (const int*)d_in[1];
  const int*   ttype     = (const int*)d_in[2];
  const float* pos_emb   = (const float*)d_in[3];
  const float* feat_emb  = (const float*)d_in[4];
  const float* qkv_w     = (const float*)d_in[5];
  const float* out_w     = (const float*)d_in[6];
  const float* q_scale   = (const float*)d_in[7];
  const float* k_scale   = (const float*)d_in[8];
  const float* ln1_w     = (const float*)d_in[9];
  const float* ln1_b     = (const float*)d_in[10];
  const float* ln2_w     = (const float*)d_in[11];
  const float* ln2_b     = (const float*)d_in[12];
  const float* fc1_w     = (const float*)d_in[13];
  const float* fc2_w     = (const float*)d_in[14];
  const float* res_a     = (const float*)d_in[15];
  const float* res_m     = (const float*)d_in[16];
  const float* skip_a    = (const float*)d_in[17];
  const float* skip_m    = (const float*)d_in[18];
  const float* lnf_w     = (const float*)d_in[19];
  const float* lnf_b     = (const float*)d_in[20];
  const float* pos_head  = (const float*)d_in[21];
  const float* feat_head = (const float*)d_in[22];
  float* out = (float*)d_out;

  float* ws    = (float*)d_ws;
  float* x     = ws;                                   // BT*C
  float* hbuf  = x     + (size_t)BT_ * C_;             // BT*C
  float* qkvb  = hbuf  + (size_t)BT_ * C_;             // BT*3C
  float* attnb = qkvb  + (size_t)BT_ * 3 * C_;         // BT*C
  float* ffb   = attnb + (size_t)BT_ * C_;             // BT*FF

  embed_kernel<<<BT_, 256, 0, stream>>>(tokens, ttype, pos_emb, feat_emb, x);

  for (int l = 0; l < L_; l++) {
    // LN1 -> h
    ln_kernel<<<BT_, 256, 0, stream>>>(x, ln1_w + l * C_, ln1_b + l * C_, hbuf);
    // qkv = h @ qkv_w[l]^T
    gemm_xwT<0><<<dim3((3 * C_) / 64, BT_ / 64), 256, 0, stream>>>(
        hbuf, qkv_w + (size_t)l * 3 * C_ * C_, qkvb, nullptr, nullptr, nullptr,
        BT_, 3 * C_, C_);
    // QKNorm + RoPE in-place
    qknorm_rope_kernel<<<BT_, 256, 0, stream>>>(qkvb, coords,
                                                q_scale + l * D_, k_scale + l * D_);
    // attention -> attnb (BT, C)
    attn_kernel<<<dim3(T_ / 4, B_ * H_), 256, 0, stream>>>(qkvb, attnb);
    // x = skip_a*x + res_a*(attnb @ out_w[l]^T)
    gemm_xwT<2><<<dim3(C_ / 64, BT_ / 64), 256, 0, stream>>>(
        attnb, out_w + (size_t)l * C_ * C_, x, x, skip_a + l, res_a + l,
        BT_, C_, C_);
    // LN2 -> h
    ln_kernel<<<BT_, 256, 0, stream>>>(x, ln2_w + l * C_, ln2_b + l * C_, hbuf);
    // ff = gelu(h @ fc1_w[l]^T)
    gemm_xwT<1><<<dim3(FF_ / 64, BT_ / 64), 256, 0, stream>>>(
        hbuf, fc1_w + (size_t)l * FF_ * C_, ffb, nullptr, nullptr, nullptr,
        BT_, FF_, C_);
    // x = skip_m*x + res_m*(ff @ fc2_w[l]^T)
    gemm_xwT<2><<<dim3(C_ / 64, BT_ / 64), 256, 0, stream>>>(
        ffb, fc2_w + (size_t)l * C_ * FF_, x, x, skip_m + l, res_m + l,
        BT_, C_, FF_);
  }

  // final LN -> h
  ln_kernel<<<BT_, 256, 0, stream>>>(x, lnf_w, lnf_b, hbuf);
  // heads -> d_out (pos logits then feat logits, concatenated flat)
  gemm_xwT<0><<<dim3((VP_ + 63) / 64, BT_ / 64), 256, 0, stream>>>(
      hbuf, pos_head, out, nullptr, nullptr, nullptr, BT_, VP_, C_);
  gemm_xwT<0><<<dim3(VF_ / 64, BT_ / 64), 256, 0, stream>>>(
      hbuf, feat_head, out + (size_t)BT_ * VP_, nullptr, nullptr, nullptr,
      BT_, VF_, C_);
}

// Round 2
// 15703.268 us; speedup vs baseline: 2.0612x; 2.0612x over previous
//
#include <hip/hip_runtime.h>
#include <math.h>

// Problem constants
constexpr int B_  = 2;
constexpr int T_  = 2048;
constexpr int H_  = 12;
constexpr int C_  = 768;
constexpr int D_  = 64;
constexpr int FF_ = 3072;
constexpr int L_  = 12;
constexpr int VP_ = 4098;
constexpr int VF_ = 4096;
constexpr int BT_ = B_ * T_;   // 4096

// ---------------------------------------------------------------------------
// Embedding gather
// ---------------------------------------------------------------------------
__global__ __launch_bounds__(256) void embed_kernel(
    const int* __restrict__ tokens, const int* __restrict__ ttype,
    const float* __restrict__ pos_w, const float* __restrict__ feat_w,
    float* __restrict__ x) {
  int row = blockIdx.x;
  int tok = tokens[row];
  const float* src;
  if (ttype[row] == 1) {
    int t = min(max(tok, 0), VF_ - 1);
    src = feat_w + (size_t)t * C_;
  } else {
    int t = min(max(tok, 0), VP_ - 1);
    src = pos_w + (size_t)t * C_;
  }
  float* dst = x + (size_t)row * C_;
  for (int c = threadIdx.x; c < C_; c += 256) dst[c] = src[c];
}

// ---------------------------------------------------------------------------
// LayerNorm over C=768; one block (256 threads) per row.
// ---------------------------------------------------------------------------
__global__ __launch_bounds__(256) void ln_kernel(
    const float* __restrict__ x, const float* __restrict__ w,
    const float* __restrict__ b, float* __restrict__ out) {
  int row = blockIdx.x;
  const float* xr = x + (size_t)row * C_;
  float vv[3];
  float s = 0.f, s2 = 0.f;
#pragma unroll
  for (int i = 0; i < 3; i++) {
    float t = xr[threadIdx.x + i * 256];
    vv[i] = t; s += t; s2 += t * t;
  }
#pragma unroll
  for (int off = 32; off; off >>= 1) {
    s  += __shfl_xor(s,  off, 64);
    s2 += __shfl_xor(s2, off, 64);
  }
  __shared__ float ss[4], ss2[4];
  int wave = threadIdx.x >> 6, lane = threadIdx.x & 63;
  if (lane == 0) { ss[wave] = s; ss2[wave] = s2; }
  __syncthreads();
  s  = ss[0] + ss[1] + ss[2] + ss[3];
  s2 = ss2[0] + ss2[1] + ss2[2] + ss2[3];
  float mean = s * (1.f / C_);
  float var  = s2 * (1.f / C_) - mean * mean;
  float inv  = 1.f / sqrtf(var + 1e-5f);
  float* orow = out + (size_t)row * C_;
#pragma unroll
  for (int i = 0; i < 3; i++) {
    int c = threadIdx.x + i * 256;
    orow[c] = (vv[i] - mean) * inv * w[c] + b[c];
  }
}

// ---------------------------------------------------------------------------
// Generic GEMM: Co[M,N] = epilogue(A[M,K] @ W[N,K]^T)
// EPI: 0 = plain, 1 = exact GELU, 2 = Co = (*skip_p)*resid + (*rs_p)*acc
// ---------------------------------------------------------------------------
template <int EPI>
__global__ __launch_bounds__(256) void gemm_xwT(
    const float* __restrict__ A, const float* __restrict__ W,
    float* Co, const float* resid,
    const float* __restrict__ skip_p, const float* __restrict__ rs_p,
    int M, int N, int K) {
  constexpr int BK = 16;
  __shared__ float As[BK][68];   // [k][m]
  __shared__ float Ws[BK][68];   // [k][n]
  int bm = blockIdx.y * 64, bn = blockIdx.x * 64;
  int tid = threadIdx.x;
  int tn = tid & 15, tm = tid >> 4;
  int lr = tid >> 2;
  int lk = (tid & 3) * 4;

  float acc[4][4] = {};

  for (int k0 = 0; k0 < K; k0 += BK) {
    const float* ap = A + (size_t)(bm + lr) * K + k0 + lk;
    float4 av = *(const float4*)ap;
    float4 wv = make_float4(0.f, 0.f, 0.f, 0.f);
    int wrow = bn + lr;
    if (wrow < N) wv = *(const float4*)(W + (size_t)wrow * K + k0 + lk);
    As[lk + 0][lr] = av.x; As[lk + 1][lr] = av.y;
    As[lk + 2][lr] = av.z; As[lk + 3][lr] = av.w;
    Ws[lk + 0][lr] = wv.x; Ws[lk + 1][lr] = wv.y;
    Ws[lk + 2][lr] = wv.z; Ws[lk + 3][lr] = wv.w;
    __syncthreads();
#pragma unroll
    for (int kk = 0; kk < BK; kk++) {
      float4 a4 = *(const float4*)&As[kk][tm * 4];
      float4 b4 = *(const float4*)&Ws[kk][tn * 4];
      float a[4] = {a4.x, a4.y, a4.z, a4.w};
      float b[4] = {b4.x, b4.y, b4.z, b4.w};
#pragma unroll
      for (int i = 0; i < 4; i++)
#pragma unroll
        for (int j = 0; j < 4; j++) acc[i][j] += a[i] * b[j];
    }
    __syncthreads();
  }

  float skip = 0.f, rs = 0.f;
  if constexpr (EPI == 2) { skip = *skip_p; rs = *rs_p; }
#pragma unroll
  for (int i = 0; i < 4; i++) {
    int m = bm + tm * 4 + i;
#pragma unroll
    for (int j = 0; j < 4; j++) {
      int n = bn + tn * 4 + j;
      if (n < N) {
        size_t idx = (size_t)m * N + n;
        float c = acc[i][j];
        if constexpr (EPI == 1) c = 0.5f * c * (1.f + erff(c * 0.70710678118654752f));
        if constexpr (EPI == 2) c = skip * resid[idx] + rs * c;
        Co[idx] = c;
      }
    }
  }
}

// ---------------------------------------------------------------------------
// QKNorm + RoPE3D, in-place on qkv (BT, 3C).
// ---------------------------------------------------------------------------
__global__ __launch_bounds__(256) void qknorm_rope_kernel(
    float* __restrict__ qkv, const int* __restrict__ coords,
    const float* __restrict__ qscale, const float* __restrict__ kscale) {
  int row = blockIdx.x;
  int wave = threadIdx.x >> 6, lane = threadIdx.x & 63;
  int c0 = coords[row * 3 + 0];
  int c1 = coords[row * 3 + 1];
  int c2 = coords[row * 3 + 2];
  for (int g = wave; g < 2 * H_; g += 4) {
    int h = g >> 1, isk = g & 1;
    size_t idx = (size_t)row * (3 * C_) + (size_t)isk * C_ + h * D_ + lane;
    float v = qkv[idx];
    float ssum = v * v;
#pragma unroll
    for (int off = 32; off; off >>= 1) ssum += __shfl_xor(ssum, off, 64);
    float n = sqrtf(ssum * (1.f / D_) + 1e-6f);
    const float* sc = isk ? kscale : qscale;
    float xn = v / n * sc[lane];
    float partner = __shfl_xor(xn, 1, 64);
    float outv = xn;
    if (lane < 60) {
      int p = lane >> 1;
      int axis = p / 10;
      int f = p - axis * 10;
      int crd = (axis == 0) ? c0 : ((axis == 1) ? c1 : c2);
      float invf = expf(-(float)f * 0.1f * 9.210340371976184f);
      float ang = (float)crd * invf;
      float sn, cs;
      sincosf(ang, &sn, &cs);
      if (lane & 1) {
        outv = partner * sn + xn * cs;
      } else {
        outv = xn * cs - partner * sn;
      }
    }
    qkv[idx] = outv;
  }
}

// ---------------------------------------------------------------------------
// Causal flash attention, 64-query tiles.
// Block = 64 queries of one (b,h); 256 threads as a 16x16 grid, each thread
// owns a 4x4 micro-tile (rows = queries, cols = head dims) of the output.
// Online softmax kept in registers: each query row's 64 scores live in the
// 16 consecutive lanes sharing tm, reduced with __shfl_xor (offsets 1..8).
// LDS: Q^T, K^T, V, P tiles at 64x72 (72 KB total -> 2 blocks/CU).
// ---------------------------------------------------------------------------
__global__ __launch_bounds__(256) void attn_kernel(
    const float* __restrict__ qkv, float* __restrict__ out) {
  int bh = blockIdx.y;
  int b = bh / H_, h = bh % H_;
  int q0 = blockIdx.x * 64;
  int tid = threadIdx.x;
  int tn = tid & 15, tm = tid >> 4;

  __shared__ float Qs[64][72];  // [d][m], pre-scaled by 1/sqrt(D)
  __shared__ float Ks[64][72];  // [d][n]
  __shared__ float Vs[64][72];  // [k][d]
  __shared__ float Ps[64][72];  // [m][n]

  // Stage Q transposed, scaled
  {
    int lr = tid >> 2;            // query row 0..63
    int ld = (tid & 3) * 16;      // dim offset
    const float* src = qkv + (size_t)(b * T_ + q0 + lr) * (3 * C_) + h * D_ + ld;
    const float sc = 0.125f;      // 1/sqrt(64)
#pragma unroll
    for (int u = 0; u < 4; u++) {
      float4 v = ((const float4*)src)[u];
      Qs[ld + u * 4 + 0][lr] = v.x * sc;
      Qs[ld + u * 4 + 1][lr] = v.y * sc;
      Qs[ld + u * 4 + 2][lr] = v.z * sc;
      Qs[ld + u * 4 + 3][lr] = v.w * sc;
    }
  }

  float accO[4][4] = {};
  float mrow[4], lrow[4];
#pragma unroll
  for (int i = 0; i < 4; i++) { mrow[i] = -1e30f; lrow[i] = 0.f; }

  for (int k0 = 0; k0 <= q0; k0 += 64) {
    __syncthreads();  // prev-iter Ps/Vs reads done; Qs published on iter 0
    // Stage K transposed + V natural
    {
      int lr = tid >> 2;          // key row 0..63
      int ld = (tid & 3) * 16;
      const float* kb = qkv + (size_t)(b * T_ + k0 + lr) * (3 * C_) + C_ + h * D_ + ld;
#pragma unroll
      for (int u = 0; u < 4; u++) {
        float4 v = ((const float4*)kb)[u];
        Ks[ld + u * 4 + 0][lr] = v.x;
        Ks[ld + u * 4 + 1][lr] = v.y;
        Ks[ld + u * 4 + 2][lr] = v.z;
        Ks[ld + u * 4 + 3][lr] = v.w;
      }
      const float* vb = kb + C_;
#pragma unroll
      for (int u = 0; u < 4; u++) {
        *(float4*)&Vs[lr][ld + u * 4] = ((const float4*)vb)[u];
      }
    }
    __syncthreads();

    // S tile: s[i][j] = Q[q0+tm*4+i] . K[k0+tn*4+j]  (Q pre-scaled)
    float s[4][4] = {};
#pragma unroll
    for (int d = 0; d < 64; d++) {
      float4 a4 = *(const float4*)&Qs[d][tm * 4];
      float4 b4 = *(const float4*)&Ks[d][tn * 4];
      float a[4] = {a4.x, a4.y, a4.z, a4.w};
      float bb[4] = {b4.x, b4.y, b4.z, b4.w};
#pragma unroll
      for (int i = 0; i < 4; i++)
#pragma unroll
        for (int j = 0; j < 4; j++) s[i][j] += a[i] * bb[j];
    }

    // Causal mask: only the diagonal tile can have invalid entries
    if (k0 == q0) {
#pragma unroll
      for (int i = 0; i < 4; i++)
#pragma unroll
        for (int j = 0; j < 4; j++)
          if (tn * 4 + j > tm * 4 + i) s[i][j] = -1e30f;
    }

    // Online softmax per row (16-lane shfl groups share a row)
#pragma unroll
    for (int i = 0; i < 4; i++) {
      float rm = fmaxf(fmaxf(s[i][0], s[i][1]), fmaxf(s[i][2], s[i][3]));
#pragma unroll
      for (int off = 1; off < 16; off <<= 1) rm = fmaxf(rm, __shfl_xor(rm, off, 64));
      float mnew = fmaxf(mrow[i], rm);
      float alpha = __expf(mrow[i] - mnew);
      mrow[i] = mnew;
      float rs = 0.f;
#pragma unroll
      for (int j = 0; j < 4; j++) {
        float p = __expf(s[i][j] - mnew);
        s[i][j] = p;
        rs += p;
      }
#pragma unroll
      for (int off = 1; off < 16; off <<= 1) rs += __shfl_xor(rs, off, 64);
      lrow[i] = lrow[i] * alpha + rs;
#pragma unroll
      for (int j = 0; j < 4; j++) accO[i][j] *= alpha;
    }

    // Publish P tile
#pragma unroll
    for (int i = 0; i < 4; i++)
      *(float4*)&Ps[tm * 4 + i][tn * 4] = make_float4(s[i][0], s[i][1], s[i][2], s[i][3]);
    __syncthreads();

    // O += P @ V  (64x64x64 register-tiled)
#pragma unroll
    for (int kk = 0; kk < 64; kk += 4) {
      float pi[4][4], vu[4][4];
#pragma unroll
      for (int i = 0; i < 4; i++) {
        float4 p4 = *(const float4*)&Ps[tm * 4 + i][kk];
        pi[i][0] = p4.x; pi[i][1] = p4.y; pi[i][2] = p4.z; pi[i][3] = p4.w;
      }
#pragma unroll
      for (int u = 0; u < 4; u++) {
        float4 v4 = *(const float4*)&Vs[kk + u][tn * 4];
        vu[u][0] = v4.x; vu[u][1] = v4.y; vu[u][2] = v4.z; vu[u][3] = v4.w;
      }
#pragma unroll
      for (int u = 0; u < 4; u++)
#pragma unroll
        for (int i = 0; i < 4; i++)
#pragma unroll
          for (int j = 0; j < 4; j++) accO[i][j] += pi[i][u] * vu[u][j];
    }
  }

  // Write out: rows q0+tm*4+i, dims tn*4+j of head h
#pragma unroll
  for (int i = 0; i < 4; i++) {
    float inv = 1.f / lrow[i];
    float4 o = make_float4(accO[i][0] * inv, accO[i][1] * inv,
                           accO[i][2] * inv, accO[i][3] * inv);
    *(float4*)(out + (size_t)(b * T_ + q0 + tm * 4 + i) * C_ + h * D_ + tn * 4) = o;
  }
}

// ---------------------------------------------------------------------------
// Orchestration
// ---------------------------------------------------------------------------
extern "C" void kernel_launch(void* const* d_in, const int* in_sizes, int n_in,
                              void* d_out, int out_size, void* d_ws, size_t ws_size,
                              hipStream_t stream) {
  const int*   tokens    = (const int*)d_in[0];
  const int*   coords    = (const int*)d_in[1];
  const int*   ttype     = (const int*)d_in[2];
  const float* pos_emb   = (const float*)d_in[3];
  const float* feat_emb  = (const float*)d_in[4];
  const float* qkv_w     = (const float*)d_in[5];
  const float* out_w     = (const float*)d_in[6];
  const float* q_scale   = (const float*)d_in[7];
  const float* k_scale   = (const float*)d_in[8];
  const float* ln1_w     = (const float*)d_in[9];
  const float* ln1_b     = (const float*)d_in[10];
  const float* ln2_w     = (const float*)d_in[11];
  const float* ln2_b     = (const float*)d_in[12];
  const float* fc1_w     = (const float*)d_in[13];
  const float* fc2_w     = (const float*)d_in[14];
  const float* res_a     = (const float*)d_in[15];
  const float* res_m     = (const float*)d_in[16];
  const float* skip_a    = (const float*)d_in[17];
  const float* skip_m    = (const float*)d_in[18];
  const float* lnf_w     = (const float*)d_in[19];
  const float* lnf_b     = (const float*)d_in[20];
  const float* pos_head  = (const float*)d_in[21];
  const float* feat_head = (const float*)d_in[22];
  float* out = (float*)d_out;

  float* ws    = (float*)d_ws;
  float* x     = ws;                                   // BT*C
  float* hbuf  = x     + (size_t)BT_ * C_;             // BT*C
  float* qkvb  = hbuf  + (size_t)BT_ * C_;             // BT*3C
  float* attnb = qkvb  + (size_t)BT_ * 3 * C_;         // BT*C
  float* ffb   = attnb + (size_t)BT_ * C_;             // BT*FF

  embed_kernel<<<BT_, 256, 0, stream>>>(tokens, ttype, pos_emb, feat_emb, x);

  for (int l = 0; l < L_; l++) {
    ln_kernel<<<BT_, 256, 0, stream>>>(x, ln1_w + l * C_, ln1_b + l * C_, hbuf);
    gemm_xwT<0><<<dim3((3 * C_) / 64, BT_ / 64), 256, 0, stream>>>(
        hbuf, qkv_w + (size_t)l * 3 * C_ * C_, qkvb, nullptr, nullptr, nullptr,
        BT_, 3 * C_, C_);
    qknorm_rope_kernel<<<BT_, 256, 0, stream>>>(qkvb, coords,
                                                q_scale + l * D_, k_scale + l * D_);
    attn_kernel<<<dim3(T_ / 64, B_ * H_), 256, 0, stream>>>(qkvb, attnb);
    gemm_xwT<2><<<dim3(C_ / 64, BT_ / 64), 256, 0, stream>>>(
        attnb, out_w + (size_t)l * C_ * C_, x, x, skip_a + l, res_a + l,
        BT_, C_, C_);
    ln_kernel<<<BT_, 256, 0, stream>>>(x, ln2_w + l * C_, ln2_b + l * C_, hbuf);
    gemm_xwT<1><<<dim3(FF_ / 64, BT_ / 64), 256, 0, stream>>>(
        hbuf, fc1_w + (size_t)l * FF_ * C_, ffb, nullptr, nullptr, nullptr,
        BT_, FF_, C_);
    gemm_xwT<2><<<dim3(C_ / 64, BT_ / 64), 256, 0, stream>>>(
        ffb, fc2_w + (size_t)l * C_ * FF_, x, x, skip_m + l, res_m + l,
        BT_, C_, FF_);
  }

  ln_kernel<<<BT_, 256, 0, stream>>>(x, lnf_w, lnf_b, hbuf);
  gemm_xwT<0><<<dim3((VP_ + 63) / 64, BT_ / 64), 256, 0, stream>>>(
      hbuf, pos_head, out, nullptr, nullptr, nullptr, BT_, VP_, C_);
  gemm_xwT<0><<<dim3(VF_ / 64, BT_ / 64), 256, 0, stream>>>(
      hbuf, feat_head, out + (size_t)BT_ * VP_, nullptr, nullptr, nullptr,
      BT_, VF_, C_);
}